// Round 1
// baseline (1749.986 us; speedup 1.0000x reference)
//
#include <hip/hip_runtime.h>
#include <stdint.h>

#define SEQ 32768
#define DIM 1024
#define FFD 4096
#define NE 8
#define CAP 5120

typedef __bf16 bf16x8 __attribute__((ext_vector_type(8)));
typedef float f32x4 __attribute__((ext_vector_type(4)));

__device__ __forceinline__ short f2bf(float f) {
  uint32_t u = __float_as_uint(f);
  uint32_t r = (u + 0x7fffu + ((u >> 16) & 1u)) >> 16;
  return (short)r;
}

__device__ __forceinline__ void async_copy16(const void* g, void* lds) {
  __builtin_amdgcn_global_load_lds((const __attribute__((address_space(1))) void*)g,
                                   (__attribute__((address_space(3))) void*)lds, 16, 0, 0);
}

// ---------------- router: logits in f64, argmax + p_max ----------------
__global__ __launch_bounds__(256) void moe_router(const float* __restrict__ x,
                                                  const float* __restrict__ Wg,
                                                  const float* __restrict__ bg,
                                                  int* __restrict__ routes,
                                                  float* __restrict__ pmax) {
  int token = blockIdx.x * 4 + (threadIdx.x >> 6);
  int lane = threadIdx.x & 63;
  const float* xr = x + (size_t)token * DIM;
  double acc[NE];
#pragma unroll
  for (int e = 0; e < NE; e++) acc[e] = 0.0;
#pragma unroll
  for (int i = 0; i < DIM / 64; i++) {
    int d = i * 64 + lane;
    double xv = (double)xr[d];
    const float* wr = Wg + (size_t)d * NE;
    float4 w0 = *(const float4*)(wr);
    float4 w1 = *(const float4*)(wr + 4);
    acc[0] += xv * (double)w0.x; acc[1] += xv * (double)w0.y;
    acc[2] += xv * (double)w0.z; acc[3] += xv * (double)w0.w;
    acc[4] += xv * (double)w1.x; acc[5] += xv * (double)w1.y;
    acc[6] += xv * (double)w1.z; acc[7] += xv * (double)w1.w;
  }
#pragma unroll
  for (int e = 0; e < NE; e++) {
#pragma unroll
    for (int off = 32; off >= 1; off >>= 1) acc[e] += __shfl_xor(acc[e], off);
  }
  if (lane == 0) {
    double l[NE];
#pragma unroll
    for (int e = 0; e < NE; e++) l[e] = acc[e] + (double)bg[e];
    int am = 0;
#pragma unroll
    for (int e = 1; e < NE; e++) if (l[e] > l[am]) am = e;  // first-max wins, matches jnp.argmax
    double s = 0.0;
#pragma unroll
    for (int e = 0; e < NE; e++) s += exp(l[e] - l[am]);
    routes[token] = am;
    pmax[token] = (float)(1.0 / s);  // p_max = softmax value at argmax
  }
}

// ---------------- scan: per-expert FCFS positions ----------------
__global__ __launch_bounds__(1024) void moe_scan(const int* __restrict__ routes,
                                                 int* __restrict__ slot_of_token,
                                                 int* __restrict__ token_of_slot,
                                                 int* __restrict__ counts) {
  __shared__ int wtot[16][NE];
  __shared__ int woff[16][NE];
  int t = threadIdx.x, lane = t & 63, w = t >> 6;
  int cnt[NE];
#pragma unroll
  for (int e = 0; e < NE; e++) cnt[e] = 0;
  int base = t * 32;
  for (int i = 0; i < 32; i++) {
    int r = routes[base + i];
#pragma unroll
    for (int e = 0; e < NE; e++) cnt[e] += (r == e) ? 1 : 0;
  }
  int incl[NE];
#pragma unroll
  for (int e = 0; e < NE; e++) {
    int v = cnt[e];
#pragma unroll
    for (int off = 1; off < 64; off <<= 1) {
      int o = __shfl_up(v, off);
      if (lane >= off) v += o;
    }
    incl[e] = v;
    if (lane == 63) wtot[w][e] = v;
  }
  __syncthreads();
  if (t < NE) {
    int run = 0;
    for (int ww = 0; ww < 16; ww++) {
      int tmp = wtot[ww][t];
      woff[ww][t] = run;
      run += tmp;
    }
    counts[t] = run;
  }
  __syncthreads();
  int pos[NE];
#pragma unroll
  for (int e = 0; e < NE; e++) pos[e] = woff[w][e] + incl[e] - cnt[e];
  for (int i = 0; i < 32; i++) {
    int tok = base + i;
    int r = routes[tok];
    int p = 0;
#pragma unroll
    for (int e = 0; e < NE; e++)
      if (r == e) { p = pos[e]; pos[e] = p + 1; }
    bool kept = p < CAP;
    int slot = kept ? r * CAP + p : NE * CAP;
    slot_of_token[tok] = slot;
    if (kept) token_of_slot[slot] = tok;
  }
}

// ---------------- gather dispatch buffer (bf16), zeros for empty slots ----------------
__global__ __launch_bounds__(256) void moe_gather(const float* __restrict__ x,
                                                  const int* __restrict__ token_of_slot,
                                                  short* __restrict__ Xd) {
  int slot = blockIdx.x;
  int tok = token_of_slot[slot];
  int t = threadIdx.x;
  short* dst = Xd + (size_t)slot * DIM + t * 4;
  short4 v;
  if (tok < 0) {
    v.x = 0; v.y = 0; v.z = 0; v.w = 0;
  } else {
    float4 f = *(const float4*)(x + (size_t)tok * DIM + t * 4);
    v.x = f2bf(f.x); v.y = f2bf(f.y); v.z = f2bf(f.z); v.w = f2bf(f.w);
  }
  *(short4*)dst = v;
}

// ---------------- convert f32 [E][K][N] -> bf16 [E][N][K] ----------------
__global__ __launch_bounds__(256) void moe_convT(const float* __restrict__ W,
                                                 short* __restrict__ WT, int K, int N) {
  __shared__ float tile[32][33];
  int e = blockIdx.z;
  const float* We = W + (size_t)e * K * N;
  short* WTe = WT + (size_t)e * K * N;
  int n0 = blockIdx.x * 32, k0 = blockIdx.y * 32;
  int tx = threadIdx.x, ty = threadIdx.y;
#pragma unroll
  for (int i = 0; i < 4; i++)
    tile[ty + i * 8][tx] = We[(size_t)(k0 + ty + i * 8) * N + n0 + tx];
  __syncthreads();
#pragma unroll
  for (int i = 0; i < 4; i++)
    WTe[(size_t)(n0 + ty + i * 8) * K + k0 + tx] = f2bf(tile[tx][ty + i * 8]);
}

// ---------------- GEMM mainloop: C[128x128] += A[128xK] * BT[128xK]^T ----------------
__device__ __forceinline__ void gemm_mainloop(const short* Ag, const short* Bg,
                                              int lda, int ldb, int K,
                                              short* As, short* Bs, f32x4 acc[4][4]) {
  int t = threadIdx.x;
  int lane = t & 63;
  int wv = t >> 6;
  int wr = wv >> 1, wc = wv & 1;
  int lrow = lane & 15, kh = lane >> 4;
  int sr = t >> 3;          // staging row within 32-row group
  int sc = (t & 7) * 8;     // staging col (elements)
  for (int kt = 0; kt < K; kt += 64) {
    const short* Ak = Ag + kt;
    const short* Bk = Bg + kt;
#pragma unroll
    for (int i = 0; i < 4; i++) {
      async_copy16(Ak + (size_t)(i * 32 + sr) * lda + sc, As + t * 8 + i * 2048);
      async_copy16(Bk + (size_t)(i * 32 + sr) * ldb + sc, Bs + t * 8 + i * 2048);
    }
    __syncthreads();
#pragma unroll
    for (int kk = 0; kk < 2; kk++) {
      bf16x8 a[4], b[4];
#pragma unroll
      for (int mi = 0; mi < 4; mi++)
        a[mi] = *(const bf16x8*)(As + (wr * 64 + mi * 16 + lrow) * 64 + kk * 32 + kh * 8);
#pragma unroll
      for (int ni = 0; ni < 4; ni++)
        b[ni] = *(const bf16x8*)(Bs + (wc * 64 + ni * 16 + lrow) * 64 + kk * 32 + kh * 8);
#pragma unroll
      for (int mi = 0; mi < 4; mi++)
#pragma unroll
        for (int ni = 0; ni < 4; ni++)
          acc[mi][ni] = __builtin_amdgcn_mfma_f32_16x16x32_bf16(a[mi], b[ni], acc[mi][ni], 0, 0, 0);
    }
    __syncthreads();
  }
}

// ---------------- GEMM1: h = gelu(Xd @ W1 + b1), bf16 out ----------------
__global__ __launch_bounds__(256) void moe_gemm1(const short* __restrict__ Xd,
                                                 const short* __restrict__ W1bT,
                                                 const float* __restrict__ b1,
                                                 short* __restrict__ h,
                                                 const int* __restrict__ counts,
                                                 int e0, size_t h_stride) {
  __shared__ short As[128 * 64];
  __shared__ short Bs[128 * 64];
  int ez = blockIdx.z, e = e0 + ez;
  int cnt = counts[e]; if (cnt > CAP) cnt = CAP;
  int m0 = blockIdx.y * 128;
  if (m0 >= cnt) return;
  int n0 = blockIdx.x * 128;
  const short* Ag = Xd + ((size_t)e * CAP + m0) * DIM;
  const short* Bg = W1bT + ((size_t)e * FFD + n0) * DIM;
  f32x4 acc[4][4];
#pragma unroll
  for (int mi = 0; mi < 4; mi++)
#pragma unroll
    for (int ni = 0; ni < 4; ni++) acc[mi][ni] = (f32x4){0.f, 0.f, 0.f, 0.f};
  gemm_mainloop(Ag, Bg, DIM, DIM, DIM, As, Bs, acc);

  short* he = h + h_stride * ez;
  int t = threadIdx.x, lane = t & 63, wv = t >> 6;
  int wr = wv >> 1, wc = wv & 1;
  int col_l = lane & 15, row_q = lane >> 4;
#pragma unroll
  for (int ni = 0; ni < 4; ni++) {
    int col = n0 + wc * 64 + ni * 16 + col_l;
    float bias = b1[(size_t)e * FFD + col];
#pragma unroll
    for (int mi = 0; mi < 4; mi++) {
      int row_base = m0 + wr * 64 + mi * 16 + row_q * 4;
#pragma unroll
      for (int j = 0; j < 4; j++) {
        float v = acc[mi][ni][j] + bias;
        float g = 0.5f * v * (1.0f + erff(v * 0.70710678118654752f));
        he[(size_t)(row_base + j) * FFD + col] = f2bf(g);
      }
    }
  }
}

// ---------------- GEMM2: out[token] = (h @ W2 + b2) * p_max, scatter ----------------
__global__ __launch_bounds__(256) void moe_gemm2(const short* __restrict__ h,
                                                 const short* __restrict__ W2bT,
                                                 const float* __restrict__ b2,
                                                 const int* __restrict__ token_of_slot,
                                                 const float* __restrict__ pmax,
                                                 float* __restrict__ out,
                                                 const int* __restrict__ counts,
                                                 int e0, size_t h_stride) {
  __shared__ short As[128 * 64];
  __shared__ short Bs[128 * 64];
  int ez = blockIdx.z, e = e0 + ez;
  int cnt = counts[e]; if (cnt > CAP) cnt = CAP;
  int m0 = blockIdx.y * 128;
  if (m0 >= cnt) return;
  int n0 = blockIdx.x * 128;
  const short* Ag = h + h_stride * ez + (size_t)m0 * FFD;
  const short* Bg = W2bT + ((size_t)e * DIM + n0) * FFD;
  f32x4 acc[4][4];
#pragma unroll
  for (int mi = 0; mi < 4; mi++)
#pragma unroll
    for (int ni = 0; ni < 4; ni++) acc[mi][ni] = (f32x4){0.f, 0.f, 0.f, 0.f};
  gemm_mainloop(Ag, Bg, FFD, FFD, FFD, As, Bs, acc);

  int t = threadIdx.x, lane = t & 63, wv = t >> 6;
  int wr = wv >> 1, wc = wv & 1;
  int col_l = lane & 15, row_q = lane >> 4;
  float bias[4];
  int cols[4];
#pragma unroll
  for (int ni = 0; ni < 4; ni++) {
    cols[ni] = n0 + wc * 64 + ni * 16 + col_l;
    bias[ni] = b2[(size_t)e * DIM + cols[ni]];
  }
#pragma unroll
  for (int mi = 0; mi < 4; mi++) {
    int row_base = m0 + wr * 64 + mi * 16 + row_q * 4;
#pragma unroll
    for (int j = 0; j < 4; j++) {
      int row = row_base + j;
      int tok = token_of_slot[e * CAP + row];
      if (tok < 0) continue;
      float f = pmax[tok];
      float* orow = out + (size_t)tok * DIM;
#pragma unroll
      for (int ni = 0; ni < 4; ni++)
        orow[cols[ni]] = (acc[mi][ni][j] + bias[ni]) * f;
    }
  }
}

// ---------------- dropped tokens: passthrough x ----------------
__global__ __launch_bounds__(256) void moe_fixup(const float* __restrict__ x,
                                                 const int* __restrict__ slot_of_token,
                                                 float* __restrict__ out) {
  int tok = blockIdx.x;
  if (slot_of_token[tok] != NE * CAP) return;
  int t = threadIdx.x;
  float4 v = *(const float4*)(x + (size_t)tok * DIM + t * 4);
  *(float4*)(out + (size_t)tok * DIM + t * 4) = v;
}

extern "C" void kernel_launch(void* const* d_in, const int* in_sizes, int n_in,
                              void* d_out, int out_size, void* d_ws, size_t ws_size,
                              hipStream_t stream) {
  (void)in_sizes; (void)n_in; (void)out_size;
  const float* x  = (const float*)d_in[0];
  const float* Wg = (const float*)d_in[1];
  const float* bg = (const float*)d_in[2];
  const float* W1 = (const float*)d_in[3];
  const float* b1 = (const float*)d_in[4];
  const float* W2 = (const float*)d_in[5];
  const float* b2 = (const float*)d_in[6];
  float* out = (float*)d_out;

  char* p = (char*)d_ws;
  auto carve = [&](size_t bytes) -> char* {
    char* r = p;
    p += (bytes + 255) & ~(size_t)255;
    return r;
  };
  short* W1bT = (short*)carve((size_t)NE * DIM * FFD * 2);
  short* W2bT = (short*)carve((size_t)NE * DIM * FFD * 2);
  short* Xd   = (short*)carve((size_t)NE * CAP * DIM * 2);
  int* routes = (int*)carve((size_t)SEQ * 4);
  float* pmax = (float*)carve((size_t)SEQ * 4);
  int* slot_of_token = (int*)carve((size_t)SEQ * 4);
  int* token_of_slot = (int*)carve((size_t)(NE * CAP) * 4);
  int* counts = (int*)carve(256);
  size_t fixed = (size_t)(p - (char*)d_ws);
  size_t h_full = (size_t)NE * CAP * FFD * 2;
  bool full = (fixed + h_full) <= ws_size;
  short* h = (short*)carve(full ? h_full : (size_t)CAP * FFD * 2);

  hipMemsetAsync(token_of_slot, 0xFF, (size_t)(NE * CAP) * 4, stream);
  moe_router<<<SEQ / 4, 256, 0, stream>>>(x, Wg, bg, routes, pmax);
  moe_scan<<<1, 1024, 0, stream>>>(routes, slot_of_token, token_of_slot, counts);
  moe_gather<<<NE * CAP, 256, 0, stream>>>(x, token_of_slot, Xd);
  moe_convT<<<dim3(FFD / 32, DIM / 32, NE), dim3(32, 8), 0, stream>>>(W1, W1bT, DIM, FFD);
  moe_convT<<<dim3(DIM / 32, FFD / 32, NE), dim3(32, 8), 0, stream>>>(W2, W2bT, FFD, DIM);

  if (full) {
    moe_gemm1<<<dim3(FFD / 128, CAP / 128, NE), 256, 0, stream>>>(
        Xd, W1bT, b1, h, counts, 0, (size_t)CAP * FFD);
    moe_gemm2<<<dim3(DIM / 128, CAP / 128, NE), 256, 0, stream>>>(
        h, W2bT, b2, token_of_slot, pmax, out, counts, 0, (size_t)CAP * FFD);
  } else {
    for (int e = 0; e < NE; e++) {
      moe_gemm1<<<dim3(FFD / 128, CAP / 128, 1), 256, 0, stream>>>(
          Xd, W1bT, b1, h, counts, e, 0);
      moe_gemm2<<<dim3(DIM / 128, CAP / 128, 1), 256, 0, stream>>>(
          h, W2bT, b2, token_of_slot, pmax, out, counts, e, 0);
    }
  }
  moe_fixup<<<SEQ, 256, 0, stream>>>(x, slot_of_token, out);
}

// Round 2
// 1243.531 us; speedup vs baseline: 1.4073x; 1.4073x over previous
//
#include <hip/hip_runtime.h>
#include <stdint.h>

#define SEQ 32768
#define DIM 1024
#define FFD 4096
#define NE 8
#define CAP 5120

typedef __bf16 bf16x8 __attribute__((ext_vector_type(8)));
typedef float f32x4 __attribute__((ext_vector_type(4)));

__device__ __forceinline__ short f2bf(float f) {
  uint32_t u = __float_as_uint(f);
  uint32_t r = (u + 0x7fffu + ((u >> 16) & 1u)) >> 16;
  return (short)r;
}

__device__ __forceinline__ void async_copy16(const void* g, void* lds) {
  __builtin_amdgcn_global_load_lds((const __attribute__((address_space(1))) void*)g,
                                   (__attribute__((address_space(3))) void*)lds, 16, 0, 0);
}

// ---------------- router: logits in f64, argmax + p_max ----------------
__global__ __launch_bounds__(256) void moe_router(const float* __restrict__ x,
                                                  const float* __restrict__ Wg,
                                                  const float* __restrict__ bg,
                                                  int* __restrict__ routes,
                                                  float* __restrict__ pmax) {
  int token = blockIdx.x * 4 + (threadIdx.x >> 6);
  int lane = threadIdx.x & 63;
  const float* xr = x + (size_t)token * DIM;
  double acc[NE];
#pragma unroll
  for (int e = 0; e < NE; e++) acc[e] = 0.0;
#pragma unroll
  for (int i = 0; i < DIM / 64; i++) {
    int d = i * 64 + lane;
    double xv = (double)xr[d];
    const float* wr = Wg + (size_t)d * NE;
    float4 w0 = *(const float4*)(wr);
    float4 w1 = *(const float4*)(wr + 4);
    acc[0] += xv * (double)w0.x; acc[1] += xv * (double)w0.y;
    acc[2] += xv * (double)w0.z; acc[3] += xv * (double)w0.w;
    acc[4] += xv * (double)w1.x; acc[5] += xv * (double)w1.y;
    acc[6] += xv * (double)w1.z; acc[7] += xv * (double)w1.w;
  }
#pragma unroll
  for (int e = 0; e < NE; e++) {
#pragma unroll
    for (int off = 32; off >= 1; off >>= 1) acc[e] += __shfl_xor(acc[e], off);
  }
  if (lane == 0) {
    double l[NE];
#pragma unroll
    for (int e = 0; e < NE; e++) l[e] = acc[e] + (double)bg[e];
    int am = 0;
#pragma unroll
    for (int e = 1; e < NE; e++) if (l[e] > l[am]) am = e;
    double s = 0.0;
#pragma unroll
    for (int e = 0; e < NE; e++) s += exp(l[e] - l[am]);
    routes[token] = am;
    pmax[token] = (float)(1.0 / s);
  }
}

// ---------------- scan: per-expert FCFS positions ----------------
__global__ __launch_bounds__(1024) void moe_scan(const int* __restrict__ routes,
                                                 int* __restrict__ slot_of_token,
                                                 int* __restrict__ token_of_slot,
                                                 int* __restrict__ counts) {
  __shared__ int wtot[16][NE];
  __shared__ int woff[16][NE];
  int t = threadIdx.x, lane = t & 63, w = t >> 6;
  int cnt[NE];
#pragma unroll
  for (int e = 0; e < NE; e++) cnt[e] = 0;
  int base = t * 32;
  for (int i = 0; i < 32; i++) {
    int r = routes[base + i];
#pragma unroll
    for (int e = 0; e < NE; e++) cnt[e] += (r == e) ? 1 : 0;
  }
  int incl[NE];
#pragma unroll
  for (int e = 0; e < NE; e++) {
    int v = cnt[e];
#pragma unroll
    for (int off = 1; off < 64; off <<= 1) {
      int o = __shfl_up(v, off);
      if (lane >= off) v += o;
    }
    incl[e] = v;
    if (lane == 63) wtot[w][e] = v;
  }
  __syncthreads();
  if (t < NE) {
    int run = 0;
    for (int ww = 0; ww < 16; ww++) {
      int tmp = wtot[ww][t];
      woff[ww][t] = run;
      run += tmp;
    }
    counts[t] = run;
  }
  __syncthreads();
  int pos[NE];
#pragma unroll
  for (int e = 0; e < NE; e++) pos[e] = woff[w][e] + incl[e] - cnt[e];
  for (int i = 0; i < 32; i++) {
    int tok = base + i;
    int r = routes[tok];
    int p = 0;
#pragma unroll
    for (int e = 0; e < NE; e++)
      if (r == e) { p = pos[e]; pos[e] = p + 1; }
    bool kept = p < CAP;
    int slot = kept ? r * CAP + p : NE * CAP;
    slot_of_token[tok] = slot;
    if (kept) token_of_slot[slot] = tok;
  }
}

// ---------------- gather dispatch buffer (bf16), zeros for empty slots ----------------
__global__ __launch_bounds__(256) void moe_gather(const float* __restrict__ x,
                                                  const int* __restrict__ token_of_slot,
                                                  short* __restrict__ Xd) {
  int slot = blockIdx.x;
  int tok = token_of_slot[slot];
  int t = threadIdx.x;
  short* dst = Xd + (size_t)slot * DIM + t * 4;
  short4 v;
  if (tok < 0) {
    v.x = 0; v.y = 0; v.z = 0; v.w = 0;
  } else {
    float4 f = *(const float4*)(x + (size_t)tok * DIM + t * 4);
    v.x = f2bf(f.x); v.y = f2bf(f.y); v.z = f2bf(f.z); v.w = f2bf(f.w);
  }
  *(short4*)dst = v;
}

// ---------------- convert f32 [E][K][N] -> bf16 [E][N][K] ----------------
__global__ __launch_bounds__(256) void moe_convT(const float* __restrict__ W,
                                                 short* __restrict__ WT, int K, int N) {
  __shared__ float tile[32][33];
  int e = blockIdx.z;
  const float* We = W + (size_t)e * K * N;
  short* WTe = WT + (size_t)e * K * N;
  int n0 = blockIdx.x * 32, k0 = blockIdx.y * 32;
  int tx = threadIdx.x, ty = threadIdx.y;
#pragma unroll
  for (int i = 0; i < 4; i++)
    tile[ty + i * 8][tx] = We[(size_t)(k0 + ty + i * 8) * N + n0 + tx];
  __syncthreads();
#pragma unroll
  for (int i = 0; i < 4; i++)
    WTe[(size_t)(n0 + ty + i * 8) * K + k0 + tx] = f2bf(tile[tx][ty + i * 8]);
}

// ---------------- GEMM mainloop: C[128x128] += A[128xK] * BT[128xK]^T ----------------
__device__ __forceinline__ void gemm_mainloop(const short* Ag, const short* Bg,
                                              int lda, int ldb, int K,
                                              short* As, short* Bs, f32x4 acc[4][4]) {
  int t = threadIdx.x;
  int lane = t & 63;
  int wv = t >> 6;
  int wr = wv >> 1, wc = wv & 1;
  int lrow = lane & 15, kh = lane >> 4;
  int sr = t >> 3;
  int sc = (t & 7) * 8;
  for (int kt = 0; kt < K; kt += 64) {
    const short* Ak = Ag + kt;
    const short* Bk = Bg + kt;
#pragma unroll
    for (int i = 0; i < 4; i++) {
      async_copy16(Ak + (size_t)(i * 32 + sr) * lda + sc, As + t * 8 + i * 2048);
      async_copy16(Bk + (size_t)(i * 32 + sr) * ldb + sc, Bs + t * 8 + i * 2048);
    }
    __syncthreads();
#pragma unroll
    for (int kk = 0; kk < 2; kk++) {
      bf16x8 a[4], b[4];
#pragma unroll
      for (int mi = 0; mi < 4; mi++)
        a[mi] = *(const bf16x8*)(As + (wr * 64 + mi * 16 + lrow) * 64 + kk * 32 + kh * 8);
#pragma unroll
      for (int ni = 0; ni < 4; ni++)
        b[ni] = *(const bf16x8*)(Bs + (wc * 64 + ni * 16 + lrow) * 64 + kk * 32 + kh * 8);
#pragma unroll
      for (int mi = 0; mi < 4; mi++)
#pragma unroll
        for (int ni = 0; ni < 4; ni++)
          acc[mi][ni] = __builtin_amdgcn_mfma_f32_16x16x32_bf16(a[mi], b[ni], acc[mi][ni], 0, 0, 0);
    }
    __syncthreads();
  }
}

// ---------------- GEMM1: h = gelu(Xd @ W1 + b1), bf16 out, LDS-staged coalesced write ----
__global__ __launch_bounds__(256) void moe_gemm1(const short* __restrict__ Xd,
                                                 const short* __restrict__ W1bT,
                                                 const float* __restrict__ b1,
                                                 short* __restrict__ h,
                                                 const int* __restrict__ counts,
                                                 int m_base, int h_rows) {
  __shared__ short smem[128 * 128];  // As(16KB) + Bs(16KB) in loop; full C tile in epilogue
  short* As = smem;
  short* Bs = smem + 128 * 64;
  int e = blockIdx.z;
  int cnt = counts[e]; if (cnt > CAP) cnt = CAP;
  int m0 = m_base + blockIdx.y * 128;
  if (m0 >= cnt) return;
  int n0 = blockIdx.x * 128;
  const short* Ag = Xd + ((size_t)e * CAP + m0) * DIM;
  const short* Bg = W1bT + ((size_t)e * FFD + n0) * DIM;
  f32x4 acc[4][4];
#pragma unroll
  for (int mi = 0; mi < 4; mi++)
#pragma unroll
    for (int ni = 0; ni < 4; ni++) acc[mi][ni] = (f32x4){0.f, 0.f, 0.f, 0.f};
  gemm_mainloop(Ag, Bg, DIM, DIM, DIM, As, Bs, acc);

  int t = threadIdx.x, lane = t & 63, wv = t >> 6;
  int wr = wv >> 1, wc = wv & 1;
  int col_l = lane & 15, row_q = lane >> 4;
  float bias[4];
  int lc[4];
#pragma unroll
  for (int ni = 0; ni < 4; ni++) {
    lc[ni] = wc * 64 + ni * 16 + col_l;
    bias[ni] = b1[(size_t)e * FFD + n0 + lc[ni]];
  }
#pragma unroll
  for (int mi = 0; mi < 4; mi++) {
#pragma unroll
    for (int j = 0; j < 4; j++) {
      int lr = wr * 64 + mi * 16 + row_q * 4 + j;
#pragma unroll
      for (int ni = 0; ni < 4; ni++) {
        float v = acc[mi][ni][j] + bias[ni];
        float g = 0.5f * v * (1.0f + erff(v * 0.70710678118654752f));
        smem[lr * 128 + lc[ni]] = f2bf(g);
      }
    }
  }
  __syncthreads();
  short* he = h + ((size_t)e * h_rows + (m0 - m_base)) * FFD + n0;
  int rr = t >> 4, cc = (t & 15) * 8;
#pragma unroll
  for (int i = 0; i < 8; i++) {
    int r = i * 16 + rr;
    *(int4*)(he + (size_t)r * FFD + cc) = *(const int4*)(smem + r * 128 + cc);
  }
}

// ---------------- GEMM2: out[token] = (h @ W2 + b2) * p_max, LDS-staged scatter ----------
__global__ __launch_bounds__(256) void moe_gemm2(const short* __restrict__ h,
                                                 const short* __restrict__ W2bT,
                                                 const float* __restrict__ b2,
                                                 const int* __restrict__ token_of_slot,
                                                 const float* __restrict__ pmax,
                                                 float* __restrict__ out,
                                                 const int* __restrict__ counts,
                                                 int m_base, int h_rows) {
  __shared__ short smem[128 * 128];
  short* As = smem;
  short* Bs = smem + 128 * 64;
  float* smemF = (float*)smem;  // 64 rows x 128 cols f32 = 32 KB
  int e = blockIdx.z;
  int cnt = counts[e]; if (cnt > CAP) cnt = CAP;
  int m0 = m_base + blockIdx.y * 128;
  if (m0 >= cnt) return;
  int n0 = blockIdx.x * 128;
  const short* Ag = h + ((size_t)e * h_rows + (m0 - m_base)) * FFD;
  const short* Bg = W2bT + ((size_t)e * DIM + n0) * FFD;
  f32x4 acc[4][4];
#pragma unroll
  for (int mi = 0; mi < 4; mi++)
#pragma unroll
    for (int ni = 0; ni < 4; ni++) acc[mi][ni] = (f32x4){0.f, 0.f, 0.f, 0.f};
  gemm_mainloop(Ag, Bg, FFD, FFD, FFD, As, Bs, acc);

  int t = threadIdx.x, lane = t & 63, wv = t >> 6;
  int wr = wv >> 1, wc = wv & 1;
  int col_l = lane & 15, row_q = lane >> 4;
  float bias[4];
  int lc[4];
#pragma unroll
  for (int ni = 0; ni < 4; ni++) {
    lc[ni] = wc * 64 + ni * 16 + col_l;
    bias[ni] = b2[(size_t)e * DIM + n0 + lc[ni]];
  }
#pragma unroll
  for (int half = 0; half < 2; half++) {
    if (wr == half) {
#pragma unroll
      for (int mi = 0; mi < 4; mi++) {
#pragma unroll
        for (int j = 0; j < 4; j++) {
          int lr = mi * 16 + row_q * 4 + j;
#pragma unroll
          for (int ni = 0; ni < 4; ni++)
            smemF[lr * 128 + lc[ni]] = acc[mi][ni][j] + bias[ni];
        }
      }
    }
    __syncthreads();
    int r32 = t >> 5, c32 = (t & 31) * 4;
#pragma unroll
    for (int i = 0; i < 8; i++) {
      int r = i * 8 + r32;
      int tok = token_of_slot[e * CAP + m0 + half * 64 + r];
      if (tok >= 0) {
        float f = pmax[tok];
        float4 v = *(const float4*)(smemF + r * 128 + c32);
        v.x *= f; v.y *= f; v.z *= f; v.w *= f;
        *(float4*)(out + (size_t)tok * DIM + n0 + c32) = v;
      }
    }
    __syncthreads();
  }
}

// ---------------- dropped tokens: passthrough x ----------------
__global__ __launch_bounds__(256) void moe_fixup(const float* __restrict__ x,
                                                 const int* __restrict__ slot_of_token,
                                                 float* __restrict__ out) {
  int tok8 = blockIdx.x * 8 + (threadIdx.x >> 5);
  int lane32 = threadIdx.x & 31;
  if (slot_of_token[tok8] != NE * CAP) return;
#pragma unroll
  for (int i = 0; i < 8; i++) {
    int c = (i * 32 + lane32) * 4;
    float4 v = *(const float4*)(x + (size_t)tok8 * DIM + c);
    *(float4*)(out + (size_t)tok8 * DIM + c) = v;
  }
}

extern "C" void kernel_launch(void* const* d_in, const int* in_sizes, int n_in,
                              void* d_out, int out_size, void* d_ws, size_t ws_size,
                              hipStream_t stream) {
  (void)in_sizes; (void)n_in; (void)out_size;
  const float* x  = (const float*)d_in[0];
  const float* Wg = (const float*)d_in[1];
  const float* bg = (const float*)d_in[2];
  const float* W1 = (const float*)d_in[3];
  const float* b1 = (const float*)d_in[4];
  const float* W2 = (const float*)d_in[5];
  const float* b2 = (const float*)d_in[6];
  float* out = (float*)d_out;

  char* p = (char*)d_ws;
  auto carve = [&](size_t bytes) -> char* {
    char* r = p;
    p += (bytes + 255) & ~(size_t)255;
    return r;
  };
  short* W1bT = (short*)carve((size_t)NE * DIM * FFD * 2);
  short* W2bT = (short*)carve((size_t)NE * DIM * FFD * 2);
  short* Xd   = (short*)carve((size_t)NE * CAP * DIM * 2);
  int* routes = (int*)carve((size_t)SEQ * 4);
  float* pmax = (float*)carve((size_t)SEQ * 4);
  int* slot_of_token = (int*)carve((size_t)SEQ * 4);
  int* token_of_slot = (int*)carve((size_t)(NE * CAP) * 4);
  int* counts = (int*)carve(256);
  size_t fixed = (size_t)(p - (char*)d_ws);

  // h chunk: as many 128-row slabs (across all experts) as ws allows
  size_t avail = (ws_size > fixed + 4096) ? (ws_size - fixed - 4096) : 0;
  size_t per_row = (size_t)NE * FFD * 2;
  int rows = (int)(avail / per_row);
  rows &= ~127;
  if (rows > CAP) rows = CAP;
  if (rows < 128) rows = 128;  // ws proven >= per-expert layout last round
  short* h = (short*)p;

  hipMemsetAsync(token_of_slot, 0xFF, (size_t)(NE * CAP) * 4, stream);
  moe_router<<<SEQ / 4, 256, 0, stream>>>(x, Wg, bg, routes, pmax);
  moe_scan<<<1, 1024, 0, stream>>>(routes, slot_of_token, token_of_slot, counts);
  moe_gather<<<NE * CAP, 256, 0, stream>>>(x, token_of_slot, Xd);
  moe_convT<<<dim3(FFD / 32, DIM / 32, NE), dim3(32, 8), 0, stream>>>(W1, W1bT, DIM, FFD);
  moe_convT<<<dim3(DIM / 32, FFD / 32, NE), dim3(32, 8), 0, stream>>>(W2, W2bT, FFD, DIM);

  for (int r0 = 0; r0 < CAP; r0 += rows) {
    int cr = (CAP - r0 < rows) ? (CAP - r0) : rows;
    moe_gemm1<<<dim3(FFD / 128, cr / 128, NE), 256, 0, stream>>>(
        Xd, W1bT, b1, h, counts, r0, rows);
    moe_gemm2<<<dim3(DIM / 128, cr / 128, NE), 256, 0, stream>>>(
        h, W2bT, b2, token_of_slot, pmax, out, counts, r0, rows);
  }
  moe_fixup<<<SEQ / 8, 256, 0, stream>>>(x, slot_of_token, out);
}